// Round 11
// baseline (14771.683 us; speedup 1.0000x reference)
//
#include <hip/hip_runtime.h>

#define H 64
#define G4 256  // 4*H

// __builtin_amdgcn_cvt_pkrtz returns a __fp16 vector; __builtin_amdgcn_fdot2
// takes _Float16 vectors. Keep both typedefs and pun through int.
typedef _Float16 f16x2 __attribute__((ext_vector_type(2)));
typedef __fp16 p16x2 __attribute__((ext_vector_type(2)));

__device__ __forceinline__ float tanh_f(float x) {
  float e = __expf(2.f * x);
  return 1.f - 2.f / (e + 1.f);
}
__device__ __forceinline__ f16x2 as_h2(int v) {
  union { int i; f16x2 h; } u; u.i = v; return u.h;
}
__device__ __forceinline__ int pack_f16(float lo, float hi) {
  union { p16x2 h; int i; } u;
  u.h = __builtin_amdgcn_cvt_pkrtz(lo, hi);
  return u.i;
}
__device__ __forceinline__ float bperm_f(int src_lane, float v) {
  return __int_as_float(
      __builtin_amdgcn_ds_bpermute(src_lane << 2, __float_as_int(v)));
}
// Workgroup barrier draining ONLY lgkmcnt (LDS); globals stay in flight.
__device__ __forceinline__ void wg_barrier() {
  asm volatile("s_waitcnt lgkmcnt(0)\n\ts_barrier" ::: "memory");
}

// Input projection, stored PRE-PERMUTED to the scan's thread layout:
// scan thread j-in-layer (w=j>>6, l=j&63) owns column (l&3)*64 + 16w+(l>>2),
// so proj thread computing original column (G,u) stores at
// pos = (u>>4)*64 + (u&15)*4 + G.  Then the scan reads xw[t*256 + j].
__global__ __launch_bounds__(G4) void proj_x(const float* __restrict__ x,
                                             const float* __restrict__ W,
                                             const float* __restrict__ b,
                                             float* __restrict__ xw) {
  const int t = blockIdx.x;
  const int j = threadIdx.x;
  const int u = j & 63, G = j >> 6;
  const int pos = ((u >> 4) << 6) | ((u & 15) << 2) | G;
  xw[(size_t)t * G4 + pos] =
      fmaf(x[2 * t], W[j], fmaf(x[2 * t + 1], W[G4 + j], b[j]));
}

// Fused 3-layer systolic LSTM scan, ONE block, 768 threads, ONE barrier/step.
// Thread (L, w, l): layer L (4 waves each), wave w owns units 16w..16w+15,
// lane l computes gate (l&3) of unit u = 16w + (l>>2)  [column (l&3)*64+u].
//
// Per step: z = base + fdot2-dot(h_own, U-col) [+ fdot2-dot(h_prev, W-col)]
// via uniform ds_read_b128 broadcast of packed-f16 h pairs; unified
// activation (one exp+rcp); 4 gates of the unit gathered INSIDE the 4-lane
// group via ds_bpermute (no barrier, no gate LDS); redundant cell update in
// the group; pair-partner h via shfl_xor(4); lanes l%8==0 publish packed h
// pairs to sh_hp[s&1][L].
//
// Sync: sh_hp is parity double-buffered: step s WRITES buf[s&1], READS
// buf[(s-1)&1] -> no write-vs-read hazard within a step. Cross-step reuse
// (write s+1 vs read s of the same buffer, and read s+1 of write s) is
// guarded by the single end-of-step barrier, because wg_barrier drains all
// LDS ops (lgkmcnt(0)) before s_barrier arrival.
__global__ __attribute__((amdgpu_flat_work_group_size(768, 768),
                          amdgpu_waves_per_eu(3, 3)))
void fused_scan(const float* __restrict__ xw,  // [T,256] permuted x@W1+b1
                const float* __restrict__ U1,
                const float* __restrict__ W2, const float* __restrict__ U2,
                const float* __restrict__ b2,
                const float* __restrict__ W3, const float* __restrict__ U3,
                const float* __restrict__ b3,
                float* __restrict__ h3out, int T) {
  __shared__ int4 sh_hp[2][3][8];  // [parity][layer][32 packed f16 h pairs]

  const int tid = (int)threadIdx.x;
  const int L = tid >> 8;   // layer (wave-uniform)
  const int j = tid & 255;  // thread-in-layer
  const int w = j >> 6;     // wave-in-layer (units 16w..16w+15)
  const int l = j & 63;     // lane
  const int G = l & 3;      // gate: 0=i,1=f,2=g(tanh),3=o
  const int u = (w << 4) | (l >> 2);  // unit
  const int col = (G << 6) | u;       // z-column in original layout

  const float* U  = (L == 0) ? U1 : ((L == 1) ? U2 : U3);
  const float* Wp = (L == 0) ? U1 : ((L == 1) ? W2 : W3);  // dummy for L0

  // f16-packed weight columns: upk[k] = (U[2k][col], U[2k+1][col])
  int upk[32], wpk[32];
#pragma unroll
  for (int k = 0; k < 32; ++k)
    upk[k] = pack_f16(U[(2 * k) * G4 + col], U[(2 * k + 1) * G4 + col]);
#pragma unroll
  for (int k = 0; k < 32; ++k)
    wpk[k] = pack_f16(Wp[(2 * k) * G4 + col], Wp[(2 * k + 1) * G4 + col]);
#pragma unroll
  for (int k = 0; k < 32; ++k) asm volatile("" : "+v"(upk[k]));
#pragma unroll
  for (int k = 0; k < 32; ++k) asm volatile("" : "+v"(wpk[k]));

  float bj = 0.f;
  if (L == 1) bj = b2[col];
  if (L == 2) bj = b3[col];

  // Unified activation constants: e = exp(z*esel); r = 1/(1+e);
  // act = ka*r + kb.  sigmoid: esel=-1, act=r.  tanh: esel=2, act=1-2r.
  const bool is_g = (G == 2);
  const float esel = is_g ? 2.f : -1.f;
  const float ka = is_g ? -2.f : 1.f;
  const float kb = is_g ? 1.f : 0.f;

  if (tid < 48) ((int4*)sh_hp)[tid] = make_int4(0, 0, 0, 0);
  wg_barrier();

  float c = 0.f;
  float nxt = 0.f;
  if (L == 0) nxt = xw[j];  // 1-step-ahead xw prefetch (permuted layout)

  const int S = T + 2;
  for (int s = 0; s < S; ++s) {
    const int t = s - L;
    const bool active = (t >= 0) && (t < T);  // uniform within layer

    if (active) {
      const int rbuf = (s - 1) & 1;
      float z0, z1 = 0.f, z2 = 0.f, z3 = 0.f;
      if (L == 0) {
        z0 = nxt;
        const int sn = (s + 1 < T) ? (s + 1) : (T - 1);
        nxt = xw[(size_t)sn * G4 + j];  // fire-and-forget prefetch
      } else {
        z0 = bj;
      }
      const int4* hb = &sh_hp[rbuf][L][0];  // own h (uniform addr broadcast)
#pragma unroll
      for (int r = 0; r < 8; ++r) {
        const int4 hv = hb[r];
        z0 = __builtin_amdgcn_fdot2(as_h2(hv.x), as_h2(upk[4 * r]), z0, false);
        z1 = __builtin_amdgcn_fdot2(as_h2(hv.y), as_h2(upk[4 * r + 1]), z1,
                                    false);
        z2 = __builtin_amdgcn_fdot2(as_h2(hv.z), as_h2(upk[4 * r + 2]), z2,
                                    false);
        z3 = __builtin_amdgcn_fdot2(as_h2(hv.w), as_h2(upk[4 * r + 3]), z3,
                                    false);
      }
      if (L > 0) {
        const int4* pb = &sh_hp[rbuf][L - 1][0];  // prev-layer h
#pragma unroll
        for (int r = 0; r < 8; ++r) {
          const int4 hv = pb[r];
          z0 = __builtin_amdgcn_fdot2(as_h2(hv.x), as_h2(wpk[4 * r]), z0,
                                      false);
          z1 = __builtin_amdgcn_fdot2(as_h2(hv.y), as_h2(wpk[4 * r + 1]), z1,
                                      false);
          z2 = __builtin_amdgcn_fdot2(as_h2(hv.z), as_h2(wpk[4 * r + 2]), z2,
                                      false);
          z3 = __builtin_amdgcn_fdot2(as_h2(hv.w), as_h2(wpk[4 * r + 3]), z3,
                                      false);
        }
      }
      const float z = (z0 + z1) + (z2 + z3);

      // per-lane activation of this thread's gate
      const float e = __expf(z * esel);
      const float r = 1.f / (1.f + e);
      const float act = fmaf(ka, r, kb);

      // gather the unit's 4 gates inside the 4-lane group (no barrier)
      const int gbase = l & ~3;
      const float gi = bperm_f(gbase + 0, act);
      const float gf = bperm_f(gbase + 1, act);
      const float gg = bperm_f(gbase + 2, act);
      const float go = bperm_f(gbase + 3, act);

      c = fmaf(gf, c, gi * gg);  // redundant in the 4-lane group
      const float h = go * tanh_f(c);
      const float hx = __shfl_xor(h, 4, 64);  // partner unit's h

      if ((l & 7) == 0)  // lane 8n publishes pair (h[2n'], h[2n'+1])
        ((int*)&sh_hp[s & 1][L][0])[(w << 3) | (l >> 3)] = pack_f16(h, hx);
      if (L == 2 && t == T - 1 && G == 0) h3out[u] = h;
    }
    wg_barrier();  // the ONLY barrier per step
  }
}

// Dense head: relu(h3@Wd1+bd1) -> relu(@Wd2+bd2) -> @Wl+bl  (all f32)
__global__ __launch_bounds__(64) void head_k(const float* __restrict__ hlast,
                                             const float* __restrict__ Wd1,
                                             const float* __restrict__ bd1,
                                             const float* __restrict__ Wd2,
                                             const float* __restrict__ bd2,
                                             const float* __restrict__ Wl,
                                             const float* __restrict__ bl,
                                             float* __restrict__ out) {
  __shared__ float s_h[H];
  __shared__ float s_a[20];
  __shared__ float s_b[20];
  const int j = threadIdx.x;
  s_h[j] = hlast[j];
  __syncthreads();
  if (j < 20) {
    float acc = bd1[j];
#pragma unroll
    for (int k = 0; k < H; ++k) acc = fmaf(s_h[k], Wd1[k * 20 + j], acc);
    s_a[j] = fmaxf(acc, 0.f);
  }
  __syncthreads();
  if (j < 20) {
    float acc = bd2[j];
#pragma unroll
    for (int k = 0; k < 20; ++k) acc = fmaf(s_a[k], Wd2[k * 20 + j], acc);
    s_b[j] = fmaxf(acc, 0.f);
  }
  __syncthreads();
  if (j < 10) {
    float acc = bl[j];
#pragma unroll
    for (int k = 0; k < 20; ++k) acc = fmaf(s_b[k], Wl[k * 10 + j], acc);
    out[j] = acc;
  }
}

extern "C" void kernel_launch(void* const* d_in, const int* in_sizes, int n_in,
                              void* d_out, int out_size, void* d_ws, size_t ws_size,
                              hipStream_t stream) {
  const float* x   = (const float*)d_in[0];
  const float* W1  = (const float*)d_in[1];
  const float* U1  = (const float*)d_in[2];
  const float* b1  = (const float*)d_in[3];
  const float* W2  = (const float*)d_in[4];
  const float* U2  = (const float*)d_in[5];
  const float* b2  = (const float*)d_in[6];
  const float* W3  = (const float*)d_in[7];
  const float* U3  = (const float*)d_in[8];
  const float* b3  = (const float*)d_in[9];
  const float* Wd1 = (const float*)d_in[10];
  const float* bd1 = (const float*)d_in[11];
  const float* Wd2 = (const float*)d_in[12];
  const float* bd2 = (const float*)d_in[13];
  const float* Wl  = (const float*)d_in[14];
  const float* bl  = (const float*)d_in[15];
  const int T = in_sizes[0] / 2;  // 16384

  // workspace: xw [T,256] | h3 [64]
  float* xw = (float*)d_ws;
  float* h3 = xw + (size_t)T * G4;

  proj_x<<<T, G4, 0, stream>>>(x, W1, b1, xw);
  fused_scan<<<1, 768, 0, stream>>>(xw, U1, W2, U2, b2, W3, U3, b3, h3, T);
  head_k<<<1, 64, 0, stream>>>(h3, Wd1, bd1, Wd2, bd2, Wl, bl, (float*)d_out);
}